// Round 6
// baseline (589.692 us; speedup 1.0000x reference)
//
#include <hip/hip_runtime.h>
#include <hip/hip_fp16.h>

#define Bv 64
#define Gv 4096
#define Cv 32
#define Sv 16
#define Lv 4
#define NSTEP 4
#define LOG2E 1.4426950408889634f
#define LN2   0.6931471805599453f
#define GAMMA 0.01f
#define RLOG2E_G 144.26950408889634f   // LOG2E / GAMMA

// raw HW transcendentals: v_exp_f32 / v_log_f32 (base-2). Safe here:
// exp2 args in [-144.3, ~0] (flushed-denormal result => term provably negligible),
// log2 args in [~1, 16+] (sum always contains the max term ~ 1).
#define EXP2R(x) __builtin_amdgcn_exp2f(x)
#define LOG2R(x) __builtin_amdgcn_logf(x)

struct __align__(8) h4 { __half2 lo, hi; };

// ROCm hip_fp16.h has no __hmax2 -> emit v_pk_max_f16 directly (gfx950 VOP3P)
__device__ __forceinline__ __half2 hmax2(__half2 a, __half2 b) {
    unsigned x = *(unsigned*)&a, y = *(unsigned*)&b, r;
    asm("v_pk_max_f16 %0, %1, %2" : "=v"(r) : "v"(x), "v"(y));
    return *(__half2*)&r;
}

__device__ __forceinline__ float wave_max(float v) {
#pragma unroll
    for (int off = 32; off > 0; off >>= 1)
        v = fmaxf(v, __shfl_xor(v, off, 64));
    return v;
}

// 256-thread block -> one atomicMax (values all >= 0, so int-bit compare == float compare)
__device__ __forceinline__ void block_atomic_max(float v, float* dst, float* smax) {
    v = wave_max(v);
    int lane = threadIdx.x & 63;
    int wid  = threadIdx.x >> 6;
    if (lane == 0) smax[wid] = v;
    __syncthreads();
    if (threadIdx.x == 0) {
        float m = fmaxf(fmaxf(smax[0], smax[1]), fmaxf(smax[2], smax[3]));
        atomicMax((int*)dst, __float_as_int(m));
    }
}

// x [B,G] -> Rt [G,B] f32 and Rth [G,B] fp16   (LDS-tiled transpose, 64 g per block)
__global__ __launch_bounds__(256) void k_transpose(const float* __restrict__ x,
                                                   float* __restrict__ Rt,
                                                   __half2* __restrict__ Rth2) {
    __shared__ float tile[64][65];
    int g0 = blockIdx.x * 64;
#pragma unroll
    for (int i = 0; i < 16; ++i) {
        int t = threadIdx.x + i * 256;
        int b = t >> 6, gi = t & 63;
        tile[gi][b] = x[b * Gv + g0 + gi];
    }
    __syncthreads();
#pragma unroll
    for (int i = 0; i < 16; ++i) {
        int t = threadIdx.x + i * 256;
        int gi = t >> 6, b = t & 63;
        Rt[(g0 + gi) * 64 + b] = tile[gi][b];
    }
#pragma unroll
    for (int i = 0; i < 8; ++i) {
        int t = threadIdx.x + i * 256;
        int gi = t >> 5, bp = t & 31;
        Rth2[(g0 + gi) * 32 + bp] =
            __floats2half2_rn(tile[gi][2 * bp], tile[gi][2 * bp + 1]);
    }
}

// Lane = (g_sub 0..3, bg 0..15). Each lane owns batches 4bg..4bg+3 of grounding
// g = g0 + g_sub. Pass 1: fp16 gathers (8B/lane) + packed products + packed max,
// p[16] staged packed (32 VGPRs -> no spill). Pass 2: one exp2 per element-step.
__global__ __launch_bounds__(256, 4) void k_clauses(const h4* __restrict__ Rth4,
                                                    const int4* __restrict__ I4,
                                                    h4* __restrict__ Csh4,
                                                    float* __restrict__ Mc) {
    __shared__ float smax[4];
    int lane = threadIdx.x & 63;
    int wid  = threadIdx.x >> 6;
    int bg   = lane & 15;
    int gsub = lane >> 4;
    int blk  = blockIdx.x;              // 8192 blocks
    int c    = blk >> 8;                // 256 blocks per clause
    int g    = ((blk & 255) << 4) + (wid << 2) + gsub;
    const int4* __restrict__ Ig = I4 + (size_t)(c * Gv + g) * Sv;

    __half2 z = __float2half2_rn(0.0f);
    __half2 plo[Sv], phi[Sv];
    __half2 mlo = z, mhi = z;           // products are >= 0
#pragma unroll
    for (int s = 0; s < Sv; ++s) {
        int4 ii = Ig[s];
        h4 a = Rth4[((size_t)(unsigned)ii.x << 4) + bg];
        h4 b = Rth4[((size_t)(unsigned)ii.y << 4) + bg];
        h4 e = Rth4[((size_t)(unsigned)ii.z << 4) + bg];
        h4 d = Rth4[((size_t)(unsigned)ii.w << 4) + bg];
        __half2 pl = __hmul2(__hmul2(a.lo, b.lo), __hmul2(e.lo, d.lo));
        __half2 ph = __hmul2(__hmul2(a.hi, b.hi), __hmul2(e.hi, d.hi));
        mlo = hmax2(mlo, pl);
        mhi = hmax2(mhi, ph);
        plo[s] = pl;
        phi[s] = ph;
    }

    float m0 = __low2float(mlo), m1 = __high2float(mlo);
    float m2 = __low2float(mhi), m3 = __high2float(mhi);
    float a0 = -m0 * RLOG2E_G, a1 = -m1 * RLOG2E_G;
    float a2 = -m2 * RLOG2E_G, a3 = -m3 * RLOG2E_G;
    float s0 = 0.f, s1 = 0.f, s2 = 0.f, s3 = 0.f;
#pragma unroll
    for (int s = 0; s < Sv; ++s) {
        s0 += EXP2R(fmaf(__low2float(plo[s]),  RLOG2E_G, a0));
        s1 += EXP2R(fmaf(__high2float(plo[s]), RLOG2E_G, a1));
        s2 += EXP2R(fmaf(__low2float(phi[s]),  RLOG2E_G, a2));
        s3 += EXP2R(fmaf(__high2float(phi[s]), RLOG2E_G, a3));
    }
    float l0 = fmaf(GAMMA * LN2, LOG2R(s0), m0);
    float l1 = fmaf(GAMMA * LN2, LOG2R(s1), m1);
    float l2 = fmaf(GAMMA * LN2, LOG2R(s2), m2);
    float l3 = fmaf(GAMMA * LN2, LOG2R(s3), m3);

    h4 outv;
    outv.lo = __floats2half2_rn(l0, l1);
    outv.hi = __floats2half2_rn(l2, l3);
    Csh4[((size_t)(c * Gv + g) << 4) + bg] = outv;

    float v = fmaxf(fmaxf(l0, l1), fmaxf(l2, l3));
    block_atomic_max(v, Mc + c, smax);      // c uniform across block
}

// coef[c] = softmax(W)[c] / max(Mc[c], 1)   -- 32 threads
__global__ __launch_bounds__(64) void k_coef(const float* __restrict__ W,
                                             const float* __restrict__ Mc,
                                             float* __restrict__ coef) {
    int c = threadIdx.x;
    float e = EXP2R(W[c] * LOG2E);
    float wsum = e;
#pragma unroll
    for (int off = 16; off > 0; off >>= 1)
        wsum += __shfl_xor(wsum, off, 64);
    coef[c] = e / (wsum * fmaxf(Mc[c], 1.0f));
}

// H[b,g] = sum_c coef[c] * Cs[c,b,g] ; track global max.  4 elements per thread.
__global__ __launch_bounds__(256) void k_combine(const h4* __restrict__ Csh4,
                                                 const float* __restrict__ coef,
                                                 float4* __restrict__ H4,
                                                 float* __restrict__ Hmax) {
    __shared__ float smax[4];
    int tid = blockIdx.x * 256 + threadIdx.x;     // 0 .. B*G/4-1
    float4 h = make_float4(0.f, 0.f, 0.f, 0.f);
#pragma unroll
    for (int c = 0; c < Cv; ++c) {
        float w = coef[c];                         // uniform -> scalar load
        h4 v = Csh4[(size_t)c * (Gv * 16) + tid];
        h.x = fmaf(w, __low2float(v.lo),  h.x);
        h.y = fmaf(w, __high2float(v.lo), h.y);
        h.z = fmaf(w, __low2float(v.hi),  h.z);
        h.w = fmaf(w, __high2float(v.hi), h.w);
    }
    H4[tid] = h;
    float v = fmaxf(fmaxf(h.x, h.y), fmaxf(h.z, h.w));
    block_atomic_max(v, Hmax, smax);
}

// ls = softor2(R, H/max(Hmax,1)) un-normalized ; track global max
__global__ __launch_bounds__(256) void k_update(const float* __restrict__ Rt,
                                                const float* __restrict__ H,
                                                const float* __restrict__ Hmax,
                                                float* __restrict__ Lraw,
                                                float* __restrict__ Lmax) {
    __shared__ float smax[4];
    int tid = blockIdx.x * 256 + threadIdx.x;
    float hden = fmaxf(Hmax[0], 1.0f);
    float hn = H[tid] / hden;
    float r  = Rt[tid];
    float mx = fmaxf(r, hn), mn = fminf(r, hn);
    float t  = EXP2R((mn - mx) * RLOG2E_G);
    float ls = fmaf(GAMMA * LN2, LOG2R(1.0f + t), mx);
    Lraw[tid] = ls;
    block_atomic_max(ls, Lmax, smax);
}

// R = Lraw / max(Lmax,1); non-last steps refresh Rt (f32) + Rth (fp16);
// last step writes output in [B,G] layout
__global__ __launch_bounds__(256) void k_norm(const float* __restrict__ Lraw,
                                              const float* __restrict__ Lmax,
                                              float* __restrict__ Rt,
                                              __half* __restrict__ Rth,
                                              float* __restrict__ out,
                                              int last) {
    int tid = blockIdx.x * 256 + threadIdx.x;
    float d = fmaxf(Lmax[0], 1.0f);
    float v = Lraw[tid] / d;
    if (last) {
        int g = tid >> 6, b = tid & 63;
        out[b * Gv + g] = v;
    } else {
        Rt[tid] = v;
        Rth[tid] = __float2half(v);
    }
}

extern "C" void kernel_launch(void* const* d_in, const int* in_sizes, int n_in,
                              void* d_out, int out_size, void* d_ws, size_t ws_size,
                              hipStream_t stream) {
    const float* x = (const float*)d_in[0];   // [64, 4096]
    const float* W = (const float*)d_in[1];   // [1, 32]
    const int*   I = (const int*)d_in[2];     // [32, 4096, 16, 4]
    float* out = (float*)d_out;               // [64, 4096]

    float*  ws   = (float*)d_ws;
    float*  Rt   = ws;                         // 262144 floats  [G,B] f32
    float*  H    = ws + 262144;                // 262144
    float*  Lraw = ws + 524288;                // 262144
    float*  maxb = ws + 786432;                // 4 * 128 floats (atomics + coef)
    __half* Rth  = (__half*)(ws + 786944);     // 262144 halves [G,B] fp16
    __half* Csh  = (__half*)(ws + 1048576);    // 8388608 halves (16 MB)

    (void)hipMemsetAsync(maxb, 0, NSTEP * 128 * sizeof(float), stream);
    k_transpose<<<Gv / 64, 256, 0, stream>>>(x, Rt, (__half2*)Rth);

    for (int step = 0; step < NSTEP; ++step) {
        float* Mc   = maxb + step * 128;  // [32] per-clause maxima
        float* Hm   = Mc + 32;
        float* Lm   = Mc + 33;
        float* coef = Mc + 64;            // [32]
        k_clauses<<<(Cv * Gv) / 16, 256, 0, stream>>>((const h4*)Rth, (const int4*)I,
                                                      (h4*)Csh, Mc);
        k_coef   <<<1, 32, 0, stream>>>(W, Mc, coef);
        k_combine<<<(Bv * Gv) / 1024, 256, 0, stream>>>((const h4*)Csh, coef,
                                                        (float4*)H, Hm);
        k_update <<<(Bv * Gv) / 256, 256, 0, stream>>>(Rt, H, Hm, Lraw, Lm);
        k_norm   <<<(Bv * Gv) / 256, 256, 0, stream>>>(Lraw, Lm, Rt, Rth, out,
                                                       step == NSTEP - 1);
    }
}